// Round 1
// baseline (323.165 us; speedup 1.0000x reference)
//
#include <hip/hip_runtime.h>
#include <math.h>

#define C_     512
#define HW_    196    // 14*14
#define B_     10
#define P_     49
#define K_     50176  // 512*2*49
#define K4_    12544  // K_/4
#define NCLS   1000
#define NT     4      // classes per block in cla_gemm

// ---------------------------------------------------------------------------
// Kernel A: build x_cat [5, 50176] directly from x, fusing the 2x2 avg pool
// and the odd-sample transpose/reinterpret/gather. One thread per element.
// ---------------------------------------------------------------------------
__global__ __launch_bounds__(256) void build_xcat(
    const float* __restrict__ x, const int* __restrict__ index_dy,
    float* __restrict__ xcat) {
  unsigned t = blockIdx.x * 256u + threadIdx.x;   // 0 .. 250879
  unsigned n = t / K_;                            // sample pair 0..4
  unsigned col = t % K_;
  unsigned b, c, h, w;
  if (col < 25088u) {            // unswap: xp[2n] flattened (c,h,w)
    b = 2u * n;
    c = col / 49u;
    unsigned hw = col % 49u;
    h = hw / 7u;  w = hw % 7u;
  } else {                       // reordered: F[i*49 + idx], F[w*3584+c*7+h]=xp
    unsigned q = col - 25088u;
    unsigned i = q / 49u, j = q % 49u;
    unsigned jj = (unsigned)index_dy[(2u * n + 1u) * 49u + j];
    unsigned p = i * 49u + jj;
    w = p / 3584u;
    unsigned rem = p % 3584u;
    c = rem / 7u;  h = rem % 7u;
    b = 2u * n + 1u;
  }
  const float* xb = x + ((b * C_ + c) * 14u + 2u * h) * 14u + 2u * w;
  float2 r0 = *(const float2*)(xb);
  float2 r1 = *(const float2*)(xb + 14);
  xcat[t] = 0.25f * (r0.x + r0.y + r1.x + r1.y);
}

// ---------------------------------------------------------------------------
// Kernel B: max over HW per (b,c). One wave per (b,c), coalesced loads,
// butterfly shuffle reduction.
// ---------------------------------------------------------------------------
__global__ __launch_bounds__(256) void maxpool_kernel(
    const float* __restrict__ x, float* __restrict__ pool) {
  int wid = (int)((blockIdx.x * 256u + threadIdx.x) >> 6);  // 0..5119
  int lane = threadIdx.x & 63;
  if (wid >= B_ * C_) return;
  const float* xr = x + (size_t)wid * HW_;
  float m = -INFINITY;
  for (int k = lane; k < HW_; k += 64) m = fmaxf(m, xr[k]);
  #pragma unroll
  for (int off = 32; off > 0; off >>= 1) m = fmaxf(m, __shfl_xor(m, off, 64));
  if (lane == 0) pool[wid] = m;
}

// ---------------------------------------------------------------------------
// Kernel C: mask = tanh(avgpool(1x1conv(x)) + cb). conv and avgpool commute.
// One block per sample: threads 0..195 compute conv at each pixel, then the
// 2x2 pool + tanh on threads 0..48.
// ---------------------------------------------------------------------------
__global__ __launch_bounds__(256) void mask_kernel(
    const float* __restrict__ x, const float* __restrict__ cw,
    const float* __restrict__ cb, float* __restrict__ out_mask) {
  __shared__ float conv[HW_];
  int b = blockIdx.x;
  int t = threadIdx.x;
  if (t < HW_) {
    const float* xb = x + (size_t)b * C_ * HW_ + t;
    float a0 = 0.f, a1 = 0.f;
    #pragma unroll 4
    for (int c = 0; c < C_; c += 2) {
      a0 += cw[c] * xb[c * HW_];
      a1 += cw[c + 1] * xb[(c + 1) * HW_];
    }
    conv[t] = a0 + a1;
  }
  __syncthreads();
  if (t < P_) {
    int i = t / 7, j = t % 7;
    float s = conv[(2 * i) * 14 + 2 * j] + conv[(2 * i) * 14 + 2 * j + 1] +
              conv[(2 * i + 1) * 14 + 2 * j] + conv[(2 * i + 1) * 14 + 2 * j + 1];
    out_mask[b * P_ + t] = tanhf(0.25f * s + cb[0]);
  }
}

// ---------------------------------------------------------------------------
// Kernel D: out_cla = sigmoid(x_cat @ W^T).  [5,50176] x [1000,50176]^T.
// Memory-bound on W (200.7 MB). NT=4 classes per block -> 250 blocks.
// Each thread: float4 strided over K, acc[NT][5] in registers.
// ---------------------------------------------------------------------------
__global__ __launch_bounds__(256) void cla_gemm(
    const float* __restrict__ xcat, const float* __restrict__ W,
    float* __restrict__ out) {
  int nb = blockIdx.x * NT;
  int t = threadIdx.x;
  float acc[NT][5];
  #pragma unroll
  for (int a = 0; a < NT; ++a)
    #pragma unroll
    for (int m = 0; m < 5; ++m) acc[a][m] = 0.f;

  const float4* X4 = (const float4*)xcat;
  const float4* W4 = (const float4*)W;

  for (int k4 = t; k4 < K4_; k4 += 256) {
    float4 xv[5];
    #pragma unroll
    for (int m = 0; m < 5; ++m) xv[m] = X4[m * K4_ + k4];
    #pragma unroll
    for (int a = 0; a < NT; ++a) {
      float4 wv = W4[(size_t)(nb + a) * K4_ + k4];
      #pragma unroll
      for (int m = 0; m < 5; ++m)
        acc[a][m] += wv.x * xv[m].x + wv.y * xv[m].y +
                     wv.z * xv[m].z + wv.w * xv[m].w;
    }
  }

  // wave butterfly reduction
  #pragma unroll
  for (int off = 32; off > 0; off >>= 1)
    #pragma unroll
    for (int a = 0; a < NT; ++a)
      #pragma unroll
      for (int m = 0; m < 5; ++m)
        acc[a][m] += __shfl_xor(acc[a][m], off, 64);

  __shared__ float red[4][NT][5];
  int wv = t >> 6, lane = t & 63;
  if (lane == 0)
    #pragma unroll
    for (int a = 0; a < NT; ++a)
      #pragma unroll
      for (int m = 0; m < 5; ++m) red[wv][a][m] = acc[a][m];
  __syncthreads();
  if (t < NT * 5) {
    int a = t / 5, m = t % 5;
    float s = red[0][a][m] + red[1][a][m] + red[2][a][m] + red[3][a][m];
    out[m * NCLS + nb + a] = 1.f / (1.f + expf(-s));
  }
}

// ---------------------------------------------------------------------------
// Kernel E: out_swap = x_avepool @ classifier_swap_w^T  -> [10, 2000].
// One wave per output column n; row of sw (512 floats) via float4.
// ---------------------------------------------------------------------------
__global__ __launch_bounds__(256) void swap_gemm(
    const float* __restrict__ pool, const float* __restrict__ sw,
    float* __restrict__ out) {
  int wid = (int)((blockIdx.x * 256u + threadIdx.x) >> 6);  // 0..1999
  int lane = threadIdx.x & 63;
  if (wid >= 2 * NCLS) return;
  const float4* swr = (const float4*)(sw + (size_t)wid * C_);
  const float4* p4 = (const float4*)pool;
  float acc[B_];
  #pragma unroll
  for (int b = 0; b < B_; ++b) acc[b] = 0.f;
  #pragma unroll
  for (int u = 0; u < 2; ++u) {
    float4 v = swr[lane + 64 * u];
    #pragma unroll
    for (int b = 0; b < B_; ++b) {
      float4 p = p4[b * (C_ / 4) + lane + 64 * u];
      acc[b] += v.x * p.x + v.y * p.y + v.z * p.z + v.w * p.w;
    }
  }
  #pragma unroll
  for (int off = 32; off > 0; off >>= 1)
    #pragma unroll
    for (int b = 0; b < B_; ++b) acc[b] += __shfl_xor(acc[b], off, 64);
  if (lane == 0)
    #pragma unroll
    for (int b = 0; b < B_; ++b) out[b * 2 * NCLS + wid] = acc[b];
}

// ---------------------------------------------------------------------------
extern "C" void kernel_launch(void* const* d_in, const int* in_sizes, int n_in,
                              void* d_out, int out_size, void* d_ws, size_t ws_size,
                              hipStream_t stream) {
  const float* x  = (const float*)d_in[0];   // [10,512,14,14]
  const float* cw = (const float*)d_in[1];   // [1,512,1,1]
  const float* cb = (const float*)d_in[2];   // [1]
  const float* Wc = (const float*)d_in[3];   // [1000, 50176]
  const float* Ws = (const float*)d_in[4];   // [2000, 512]
  const int*  idx = (const int*)d_in[5];     // [10,49] int32
  float* out = (float*)d_out;                // 5000 | 20000 | 490

  float* xcat = (float*)d_ws;                // 250880 floats
  float* pool = xcat + 5 * K_;               // 5120 floats

  build_xcat<<<980, 256, 0, stream>>>(x, idx, xcat);
  maxpool_kernel<<<(B_ * C_ + 3) / 4, 256, 0, stream>>>(x, pool);
  mask_kernel<<<B_, 256, 0, stream>>>(x, cw, cb, out + 25000);
  cla_gemm<<<NCLS / NT, 256, 0, stream>>>(xcat, Wc, out);
  swap_gemm<<<2 * NCLS / 4, 256, 0, stream>>>(pool, Ws, out + 5000);
}

// Round 3
// 299.262 us; speedup vs baseline: 1.0799x; 1.0799x over previous
//
#include <hip/hip_runtime.h>
#include <math.h>

#define C_     512
#define HW_    196    // 14*14
#define B_     10
#define P_     49
#define K_     50176  // 512*2*49
#define K4_    12544  // K_/4
#define NCLS   1000
#define NT     4      // classes per block-group in cla partial
#define KCH    4      // K-chunks (split-K)
#define KC4_   3136   // K4_/KCH

// ws layout (floats): xcat[250880] | pool[5120] | conv_part[8*1960] | cla_part[4*5000]

// ---------------------------------------------------------------------------
// Kernel 1 "prep": blocks [0,980) build x_cat; [980,2260) maxpool; [2260,2340)
// conv-mask partial sums over 64-channel groups.
// ---------------------------------------------------------------------------
__global__ __launch_bounds__(256) void prep_kernel(
    const float* __restrict__ x, const int* __restrict__ index_dy,
    const float* __restrict__ cw,
    float* __restrict__ xcat, float* __restrict__ pool,
    float* __restrict__ conv_part) {
  unsigned blk = blockIdx.x;
  if (blk < 980u) {
    // ---- build_xcat: fused 2x2 avgpool + odd-sample transpose/gather ----
    unsigned t = blk * 256u + threadIdx.x;   // 0 .. 250879
    unsigned n = t / K_;
    unsigned col = t % K_;
    unsigned b, c, h, w;
    if (col < 25088u) {          // unswap: xp[2n] flattened (c,h,w)
      b = 2u * n;
      c = col / 49u;
      unsigned hw = col % 49u;
      h = hw / 7u;  w = hw % 7u;
    } else {                     // reordered: F[i*49+idx], F[w*3584+c*7+h]=xp
      unsigned q = col - 25088u;
      unsigned i = q / 49u, j = q % 49u;
      unsigned jj = (unsigned)index_dy[(2u * n + 1u) * 49u + j];
      unsigned p = i * 49u + jj;
      w = p / 3584u;
      unsigned rem = p % 3584u;
      c = rem / 7u;  h = rem % 7u;
      b = 2u * n + 1u;
    }
    const float* xb = x + ((b * C_ + c) * 14u + 2u * h) * 14u + 2u * w;
    float2 r0 = *(const float2*)(xb);
    float2 r1 = *(const float2*)(xb + 14);
    xcat[t] = 0.25f * (r0.x + r0.y + r1.x + r1.y);
  } else if (blk < 2260u) {
    // ---- maxpool over HW per (b,c): one wave each ----
    int lb = (int)blk - 980;
    int wid = lb * 4 + (int)(threadIdx.x >> 6);   // 0..5119
    int lane = threadIdx.x & 63;
    const float* xr = x + (size_t)wid * HW_;
    float m = -INFINITY;
    for (int k = lane; k < HW_; k += 64) m = fmaxf(m, xr[k]);
    #pragma unroll
    for (int off = 32; off > 0; off >>= 1) m = fmaxf(m, __shfl_xor(m, off, 64));
    if (lane == 0) pool[wid] = m;
  } else {
    // ---- conv-mask partials: block = (b, 64-channel group g) ----
    int lb = (int)blk - 2260;     // 0..79
    int b = lb / 8, g = lb % 8;
    int t = threadIdx.x;
    if (t < HW_) {
      const float* xb = x + ((size_t)b * C_ + g * 64u) * HW_ + t;
      float a0 = 0.f, a1 = 0.f;
      #pragma unroll 8
      for (int c = 0; c < 64; c += 2) {
        a0 += cw[g * 64 + c] * xb[c * HW_];
        a1 += cw[g * 64 + c + 1] * xb[(c + 1) * HW_];
      }
      conv_part[(g * B_ + b) * HW_ + t] = a0 + a1;
    }
  }
}

// ---------------------------------------------------------------------------
// Kernel 2 "main2": blocks [0,1000) cla split-K partials; [1000,1500)
// swap_gemm; block 1500 mask finish (pool + tanh over conv partials).
// ---------------------------------------------------------------------------
__global__ __launch_bounds__(256) void main2_kernel(
    const float* __restrict__ xcat, const float* __restrict__ pool,
    const float* __restrict__ W, const float* __restrict__ Ws,
    const float* __restrict__ conv_part, const float* __restrict__ cb,
    float* __restrict__ cla_part, float* __restrict__ out) {
  __shared__ float red[4][NT][5];
  unsigned blk = blockIdx.x;
  int t = threadIdx.x;
  if (blk < 1000u) {
    // ---- cla partial: classes [nb,nb+4), K4 range [kbase, kbase+3136) ----
    int kc = (int)blk / 250;
    int nb = ((int)blk % 250) * NT;
    int kbase = kc * KC4_;
    float acc[NT][5];
    #pragma unroll
    for (int a = 0; a < NT; ++a)
      #pragma unroll
      for (int m = 0; m < 5; ++m) acc[a][m] = 0.f;
    const float4* X4 = (const float4*)xcat;
    const float4* W4 = (const float4*)W;
    for (int k4 = kbase + t; k4 < kbase + KC4_; k4 += 256) {
      float4 xv[5];
      #pragma unroll
      for (int m = 0; m < 5; ++m) xv[m] = X4[m * K4_ + k4];
      #pragma unroll
      for (int a = 0; a < NT; ++a) {
        float4 wv = W4[(size_t)(nb + a) * K4_ + k4];
        #pragma unroll
        for (int m = 0; m < 5; ++m)
          acc[a][m] += wv.x * xv[m].x + wv.y * xv[m].y +
                       wv.z * xv[m].z + wv.w * xv[m].w;
      }
    }
    #pragma unroll
    for (int off = 32; off > 0; off >>= 1)
      #pragma unroll
      for (int a = 0; a < NT; ++a)
        #pragma unroll
        for (int m = 0; m < 5; ++m)
          acc[a][m] += __shfl_xor(acc[a][m], off, 64);
    int wv = t >> 6, lane = t & 63;
    if (lane == 0)
      #pragma unroll
      for (int a = 0; a < NT; ++a)
        #pragma unroll
        for (int m = 0; m < 5; ++m) red[wv][a][m] = acc[a][m];
    __syncthreads();
    if (t < NT * 5) {
      int a = t / 5, m = t % 5;
      float s = red[0][a][m] + red[1][a][m] + red[2][a][m] + red[3][a][m];
      cla_part[kc * 5000 + m * NCLS + nb + a] = s;
    }
  } else if (blk < 1500u) {
    // ---- swap_gemm: out_swap = pool @ Ws^T, one wave per column ----
    int lb = (int)blk - 1000;
    int wid = lb * 4 + (t >> 6);   // 0..1999
    int lane = t & 63;
    const float4* swr = (const float4*)(Ws + (size_t)wid * C_);
    const float4* p4 = (const float4*)pool;
    float acc[B_];
    #pragma unroll
    for (int b = 0; b < B_; ++b) acc[b] = 0.f;
    #pragma unroll
    for (int u = 0; u < 2; ++u) {
      float4 v = swr[lane + 64 * u];
      #pragma unroll
      for (int b = 0; b < B_; ++b) {
        float4 p = p4[b * (C_ / 4) + lane + 64 * u];
        acc[b] += v.x * p.x + v.y * p.y + v.z * p.z + v.w * p.w;
      }
    }
    #pragma unroll
    for (int off = 32; off > 0; off >>= 1)
      #pragma unroll
      for (int b = 0; b < B_; ++b) acc[b] += __shfl_xor(acc[b], off, 64);
    if (lane == 0)
      #pragma unroll
      for (int b = 0; b < B_; ++b) out[5000 + b * 2 * NCLS + wid] = acc[b];
  } else {
    // ---- mask finish: 2x2 pool of conv partials + tanh ----
    // 490 outputs, 256 threads -> loop (t, t+256). BUG FIX from R2: the
    // single `if (t < 490)` left elements 256..489 unwritten.
    for (int t0 = t; t0 < B_ * P_; t0 += 256) {
      int b = t0 / P_, p = t0 % P_;
      int i = p / 7, j = p % 7;
      int q00 = (2 * i) * 14 + 2 * j;
      float s = 0.f;
      #pragma unroll
      for (int g = 0; g < 8; ++g) {
        const float* cp = conv_part + (g * B_ + b) * HW_;
        s += cp[q00] + cp[q00 + 1] + cp[q00 + 14] + cp[q00 + 15];
      }
      out[25000 + t0] = tanhf(0.25f * s + cb[0]);
    }
  }
}

// ---------------------------------------------------------------------------
// Kernel 3: sum the 4 split-K partials + sigmoid.
// ---------------------------------------------------------------------------
__global__ __launch_bounds__(256) void finish_kernel(
    const float* __restrict__ cla_part, float* __restrict__ out) {
  int i = blockIdx.x * 256 + threadIdx.x;
  if (i < 5 * NCLS) {
    float s = cla_part[i] + cla_part[5000 + i] +
              cla_part[10000 + i] + cla_part[15000 + i];
    out[i] = 1.f / (1.f + expf(-s));
  }
}

// ---------------------------------------------------------------------------
extern "C" void kernel_launch(void* const* d_in, const int* in_sizes, int n_in,
                              void* d_out, int out_size, void* d_ws, size_t ws_size,
                              hipStream_t stream) {
  const float* x  = (const float*)d_in[0];   // [10,512,14,14]
  const float* cw = (const float*)d_in[1];   // [1,512,1,1]
  const float* cb = (const float*)d_in[2];   // [1]
  const float* Wc = (const float*)d_in[3];   // [1000, 50176]
  const float* Ws = (const float*)d_in[4];   // [2000, 512]
  const int*  idx = (const int*)d_in[5];     // [10,49] int32
  float* out = (float*)d_out;                // 5000 | 20000 | 490

  float* xcat      = (float*)d_ws;           // 250880
  float* pool      = xcat + 5 * K_;          // 5120
  float* conv_part = pool + B_ * C_;         // 8*1960 = 15680
  float* cla_part  = conv_part + 8 * B_ * HW_; // 4*5000 = 20000

  prep_kernel<<<2340, 256, 0, stream>>>(x, idx, cw, xcat, pool, conv_part);
  main2_kernel<<<1501, 256, 0, stream>>>(xcat, pool, Wc, Ws, conv_part, cb,
                                         cla_part, out);
  finish_kernel<<<20, 256, 0, stream>>>(cla_part, out);
}

// Round 5
// 289.875 us; speedup vs baseline: 1.1148x; 1.0324x over previous
//
#include <hip/hip_runtime.h>
#include <math.h>

#define C_     512
#define HW_    196    // 14*14
#define B_     10
#define P_     49
#define K_     50176  // 512*2*49
#define K4_    12544  // K_/4
#define NCLS   1000
#define NT     8      // classes per block-group in cla partial
#define NG     125    // class groups (NCLS/NT)
#define KCH    8      // K-chunks (split-K)
#define KC4_   1568   // K4_/KCH

// native vector type for __builtin_nontemporal_load (HIP_vector_type is a
// struct and the builtin rejects it)
typedef float vfloat4 __attribute__((ext_vector_type(4)));

// ws layout (floats): xcat[250880] | pool[5120] | conv_part[8*1960] | cla_part[8*5000]

// ---------------------------------------------------------------------------
// Kernel 1 "prep": blocks [0,980) build x_cat; [980,2260) maxpool; [2260,2340)
// conv-mask partial sums over 64-channel groups.
// ---------------------------------------------------------------------------
__global__ __launch_bounds__(256) void prep_kernel(
    const float* __restrict__ x, const int* __restrict__ index_dy,
    const float* __restrict__ cw,
    float* __restrict__ xcat, float* __restrict__ pool,
    float* __restrict__ conv_part) {
  unsigned blk = blockIdx.x;
  if (blk < 980u) {
    // ---- build_xcat: fused 2x2 avgpool + odd-sample transpose/gather ----
    unsigned t = blk * 256u + threadIdx.x;   // 0 .. 250879
    unsigned n = t / K_;
    unsigned col = t % K_;
    unsigned b, c, h, w;
    if (col < 25088u) {          // unswap: xp[2n] flattened (c,h,w)
      b = 2u * n;
      c = col / 49u;
      unsigned hw = col % 49u;
      h = hw / 7u;  w = hw % 7u;
    } else {                     // reordered: F[i*49+idx], F[w*3584+c*7+h]=xp
      unsigned q = col - 25088u;
      unsigned i = q / 49u, j = q % 49u;
      unsigned jj = (unsigned)index_dy[(2u * n + 1u) * 49u + j];
      unsigned p = i * 49u + jj;
      w = p / 3584u;
      unsigned rem = p % 3584u;
      c = rem / 7u;  h = rem % 7u;
      b = 2u * n + 1u;
    }
    const float* xb = x + ((b * C_ + c) * 14u + 2u * h) * 14u + 2u * w;
    float2 r0 = *(const float2*)(xb);
    float2 r1 = *(const float2*)(xb + 14);
    xcat[t] = 0.25f * (r0.x + r0.y + r1.x + r1.y);
  } else if (blk < 2260u) {
    // ---- maxpool over HW per (b,c): one wave each, float4 loads ----
    int lb = (int)blk - 980;
    int wid = lb * 4 + (int)(threadIdx.x >> 6);   // 0..5119
    int lane = threadIdx.x & 63;
    const float4* xr = (const float4*)(x + (size_t)wid * HW_);
    float m = -INFINITY;
    if (lane < 49) {              // 49 float4 = 196 floats
      float4 v = xr[lane];
      m = fmaxf(fmaxf(v.x, v.y), fmaxf(v.z, v.w));
    }
    #pragma unroll
    for (int off = 32; off > 0; off >>= 1) m = fmaxf(m, __shfl_xor(m, off, 64));
    if (lane == 0) pool[wid] = m;
  } else {
    // ---- conv-mask partials: block = (b, 64-channel group g) ----
    int lb = (int)blk - 2260;     // 0..79
    int b = lb / 8, g = lb % 8;
    int t = threadIdx.x;
    if (t < HW_) {
      const float* xb = x + ((size_t)b * C_ + g * 64u) * HW_ + t;
      float a0 = 0.f, a1 = 0.f;
      #pragma unroll 8
      for (int c = 0; c < 64; c += 2) {
        a0 += cw[g * 64 + c] * xb[c * HW_];
        a1 += cw[g * 64 + c + 1] * xb[(c + 1) * HW_];
      }
      conv_part[(g * B_ + b) * HW_ + t] = a0 + a1;
    }
  }
}

// ---------------------------------------------------------------------------
// Kernel 2 "main2": blocks [0,1000) cla split-K partials (8 classes x 1/8 K
// each); [1000,1500) swap_gemm; block 1500 mask finish.
// W loads are nontemporal (each W line touched exactly once -> don't evict
// xcat from L2).
// ---------------------------------------------------------------------------
__global__ __launch_bounds__(256) void main2_kernel(
    const float* __restrict__ xcat, const float* __restrict__ pool,
    const float* __restrict__ W, const float* __restrict__ Ws,
    const float* __restrict__ conv_part, const float* __restrict__ cb,
    float* __restrict__ cla_part, float* __restrict__ out) {
  __shared__ float red[4][NT][5];
  unsigned blk = blockIdx.x;
  int t = threadIdx.x;
  if (blk < 1000u) {
    // ---- cla partial: classes [nb,nb+8), K4 range [kbase, kbase+1568) ----
    int kc = (int)blk / NG;          // 0..7
    int nb = ((int)blk % NG) * NT;   // 0..992
    int kbase = kc * KC4_;
    float acc[NT][5];
    #pragma unroll
    for (int a = 0; a < NT; ++a)
      #pragma unroll
      for (int m = 0; m < 5; ++m) acc[a][m] = 0.f;
    const float4* X4 = (const float4*)xcat;
    const vfloat4* W4 = (const vfloat4*)W;
    for (int k4 = kbase + t; k4 < kbase + KC4_; k4 += 256) {
      float4 xv[5];
      #pragma unroll
      for (int m = 0; m < 5; ++m) xv[m] = X4[m * K4_ + k4];
      #pragma unroll
      for (int a = 0; a < NT; ++a) {
        vfloat4 wv = __builtin_nontemporal_load(&W4[(size_t)(nb + a) * K4_ + k4]);
        #pragma unroll
        for (int m = 0; m < 5; ++m)
          acc[a][m] += wv.x * xv[m].x + wv.y * xv[m].y +
                       wv.z * xv[m].z + wv.w * xv[m].w;
      }
    }
    #pragma unroll
    for (int off = 32; off > 0; off >>= 1)
      #pragma unroll
      for (int a = 0; a < NT; ++a)
        #pragma unroll
        for (int m = 0; m < 5; ++m)
          acc[a][m] += __shfl_xor(acc[a][m], off, 64);
    int wv = t >> 6, lane = t & 63;
    if (lane == 0)
      #pragma unroll
      for (int a = 0; a < NT; ++a)
        #pragma unroll
        for (int m = 0; m < 5; ++m) red[wv][a][m] = acc[a][m];
    __syncthreads();
    if (t < NT * 5) {
      int a = t / 5, m = t % 5;
      float s = red[0][a][m] + red[1][a][m] + red[2][a][m] + red[3][a][m];
      cla_part[kc * 5000 + m * NCLS + nb + a] = s;
    }
  } else if (blk < 1500u) {
    // ---- swap_gemm: out_swap = pool @ Ws^T, one wave per column ----
    int lb = (int)blk - 1000;
    int wid = lb * 4 + (t >> 6);   // 0..1999
    int lane = t & 63;
    const float4* swr = (const float4*)(Ws + (size_t)wid * C_);
    const float4* p4 = (const float4*)pool;
    float acc[B_];
    #pragma unroll
    for (int b = 0; b < B_; ++b) acc[b] = 0.f;
    #pragma unroll
    for (int u = 0; u < 2; ++u) {
      float4 v = swr[lane + 64 * u];
      #pragma unroll
      for (int b = 0; b < B_; ++b) {
        float4 p = p4[b * (C_ / 4) + lane + 64 * u];
        acc[b] += v.x * p.x + v.y * p.y + v.z * p.z + v.w * p.w;
      }
    }
    #pragma unroll
    for (int off = 32; off > 0; off >>= 1)
      #pragma unroll
      for (int b = 0; b < B_; ++b) acc[b] += __shfl_xor(acc[b], off, 64);
    if (lane == 0)
      #pragma unroll
      for (int b = 0; b < B_; ++b) out[5000 + b * 2 * NCLS + wid] = acc[b];
  } else {
    // ---- mask finish: 2x2 pool of conv partials + tanh (490 outputs) ----
    for (int t0 = t; t0 < B_ * P_; t0 += 256) {
      int b = t0 / P_, p = t0 % P_;
      int i = p / 7, j = p % 7;
      int q00 = (2 * i) * 14 + 2 * j;
      float s = 0.f;
      #pragma unroll
      for (int g = 0; g < 8; ++g) {
        const float* cp = conv_part + (g * B_ + b) * HW_;
        s += cp[q00] + cp[q00 + 1] + cp[q00 + 14] + cp[q00 + 15];
      }
      out[25000 + t0] = tanhf(0.25f * s + cb[0]);
    }
  }
}

// ---------------------------------------------------------------------------
// Kernel 3: sum the 8 split-K partials + sigmoid.
// ---------------------------------------------------------------------------
__global__ __launch_bounds__(256) void finish_kernel(
    const float* __restrict__ cla_part, float* __restrict__ out) {
  int i = blockIdx.x * 256 + threadIdx.x;
  if (i < 5 * NCLS) {
    float s = 0.f;
    #pragma unroll
    for (int kc = 0; kc < KCH; ++kc) s += cla_part[kc * 5000 + i];
    out[i] = 1.f / (1.f + expf(-s));
  }
}

// ---------------------------------------------------------------------------
extern "C" void kernel_launch(void* const* d_in, const int* in_sizes, int n_in,
                              void* d_out, int out_size, void* d_ws, size_t ws_size,
                              hipStream_t stream) {
  const float* x  = (const float*)d_in[0];   // [10,512,14,14]
  const float* cw = (const float*)d_in[1];   // [1,512,1,1]
  const float* cb = (const float*)d_in[2];   // [1]
  const float* Wc = (const float*)d_in[3];   // [1000, 50176]
  const float* Ws = (const float*)d_in[4];   // [2000, 512]
  const int*  idx = (const int*)d_in[5];     // [10,49] int32
  float* out = (float*)d_out;                // 5000 | 20000 | 490

  float* xcat      = (float*)d_ws;             // 250880
  float* pool      = xcat + 5 * K_;            // 5120
  float* conv_part = pool + B_ * C_;           // 8*1960 = 15680
  float* cla_part  = conv_part + 8 * B_ * HW_; // 8*5000 = 40000

  prep_kernel<<<2340, 256, 0, stream>>>(x, idx, cw, xcat, pool, conv_part);
  main2_kernel<<<1501, 256, 0, stream>>>(xcat, pool, Wc, Ws, conv_part, cb,
                                         cla_part, out);
  finish_kernel<<<20, 256, 0, stream>>>(cla_part, out);
}